// Round 1
// baseline (162.029 us; speedup 1.0000x reference)
//
#include <hip/hip_runtime.h>
#include <stdint.h>

typedef float    f32x4  __attribute__((ext_vector_type(4)));
typedef __bf16   bf16x8 __attribute__((ext_vector_type(8)));
typedef short    s16x8  __attribute__((ext_vector_type(8)));
typedef int      i32x4  __attribute__((ext_vector_type(4)));
typedef unsigned short u16x4 __attribute__((ext_vector_type(4)));

#define DEVINL __device__ __forceinline__

DEVINL unsigned short f2bf(float f) {
  unsigned u = __builtin_bit_cast(unsigned, f);
  return (unsigned short)((u + 0x7fffu + ((u >> 16) & 1u)) >> 16);
}

DEVINL f32x4 mfma16(bf16x8 a, bf16x8 b, f32x4 c) {
  return __builtin_amdgcn_mfma_f32_16x16x32_bf16(a, b, c, 0, 0, 0);
}

DEVINL bf16x8 lds_frag(const unsigned char* p) {
  return __builtin_bit_cast(bf16x8, *(const s16x8*)p);
}

template <int CTRL>
DEVINL float dppf(float x) {
  int xi = __builtin_bit_cast(int, x);
  return __builtin_bit_cast(float, __builtin_amdgcn_update_dpp(xi, xi, CTRL, 0xF, 0xF, true));
}
// reduce across the 16 lanes of a DPP row (lanes sharing l>>4 group boundaries)
DEVINL float redmax16(float v) {
  v = fmaxf(v, dppf<0xB1>(v));   // quad_perm xor1
  v = fmaxf(v, dppf<0x4E>(v));   // quad_perm xor2
  v = fmaxf(v, dppf<0x141>(v));  // row_half_mirror (quad<->quad)
  v = fmaxf(v, dppf<0x140>(v));  // row_mirror (half<->half)
  return v;
}
DEVINL float redsum16(float v) {
  v += dppf<0xB1>(v);
  v += dppf<0x4E>(v);
  v += dppf<0x141>(v);
  v += dppf<0x140>(v);
  return v;
}

// ---------------- prep: convert the 4 weight matrices to bf16 ----------------
__global__ __launch_bounds__(256) void prep_w_kernel(
    const float* __restrict__ wq, const float* __restrict__ wk,
    const float* __restrict__ wv, const float* __restrict__ wp,
    unsigned short* __restrict__ wbf) {
  int id = blockIdx.x * 256 + threadIdx.x;  // 16384 threads, 4 floats each
  int m = id >> 12;
  const float* src = (m == 0) ? wq : (m == 1) ? wk : (m == 2) ? wv : wp;
  f32x4 v = ((const f32x4*)src)[id & 4095];
  u16x4 o;
  o[0] = f2bf(v[0]); o[1] = f2bf(v[1]); o[2] = f2bf(v[2]); o[3] = f2bf(v[3]);
  ((u16x4*)wbf)[id] = o;
}

// ---------------- QKV: X^T staging + 3 GEMMs; V emitted transposed ----------
// x, wav: [128 c][8192 s] f32.  Outputs: Qb,Kb [8192 s][128 j] bf16; Vt [128 j][8192 s] bf16.
__global__ __launch_bounds__(256) void qkv_kernel(
    const float* __restrict__ x, const float* __restrict__ wav,
    const unsigned short* __restrict__ wbf,
    const float* __restrict__ bq, const float* __restrict__ bk, const float* __restrict__ bv,
    unsigned short* __restrict__ Qb, unsigned short* __restrict__ Kb,
    unsigned short* __restrict__ Vt) {
  __shared__ __align__(16) unsigned char sm[32768];  // Xt[64s][128c] @0, Ft @16384
  const int tid = threadIdx.x;
  const int s0 = blockIdx.x * 64;

  {  // transpose-stage: global [c][s] f32 -> LDS [s][c] bf16 (XOR-swizzled rows of 256B)
    const int c = tid >> 1, half = tid & 1;
    const float* xs = x + c * 8192 + s0 + half * 32;
    const float* fs = wav + c * 8192 + s0 + half * 32;
#pragma unroll
    for (int i = 0; i < 8; ++i) {
      f32x4 vx = *(const f32x4*)(xs + i * 4);
      f32x4 vf = *(const f32x4*)(fs + i * 4);
#pragma unroll
      for (int j = 0; j < 4; ++j) {
        int s = half * 32 + i * 4 + j;
        int off = (c * 2) ^ ((s & 7) << 4);
        *(unsigned short*)(sm + s * 256 + off) = f2bf(vx[j]);
        *(unsigned short*)(sm + 16384 + s * 256 + off) = f2bf(vf[j]);
      }
    }
  }
  __syncthreads();

  const int w = tid >> 6, l = tid & 63, lr = l & 15, lh = l >> 4;
  const int arow = w * 16 + lr;
  const int aswz = (lr & 7) << 4;

#pragma unroll 1
  for (int g = 0; g < 3; ++g) {  // 0: Q from Xt, 1: K from Ft, 2: V from Ft
    const unsigned char* asrc = sm + (g == 0 ? 0 : 16384) + arow * 256;
    const unsigned char* wsrc = (const unsigned char*)wbf + g * 32768;
    f32x4 acc[8];
#pragma unroll
    for (int jt = 0; jt < 8; ++jt) acc[jt] = (f32x4){0.f, 0.f, 0.f, 0.f};
#pragma unroll
    for (int ks = 0; ks < 4; ++ks) {
      bf16x8 a = lds_frag(asrc + ((ks * 64 + lh * 16) ^ aswz));
#pragma unroll
      for (int jt = 0; jt < 8; ++jt) {
        bf16x8 bb = __builtin_bit_cast(
            bf16x8, *(const s16x8*)(wsrc + (jt * 16 + lr) * 256 + ks * 64 + lh * 16));
        acc[jt] = mfma16(a, bb, acc[jt]);
      }
    }
    if (g < 2) {
      const float* bias = g ? bk : bq;
      unsigned short* outp = g ? Kb : Qb;
#pragma unroll
      for (int jt = 0; jt < 8; ++jt) {
        float bb = bias[jt * 16 + lr];
#pragma unroll
        for (int r = 0; r < 4; ++r) {
          int row = s0 + w * 16 + lh * 4 + r;
          outp[row * 128 + jt * 16 + lr] = f2bf(acc[jt][r] + bb);
        }
      }
    } else {
      __syncthreads();  // everyone done reading Xt; reuse sm[0..16K) as Vt_lds[128 j][64 s]
#pragma unroll
      for (int jt = 0; jt < 8; ++jt) {
        float bb = bv[jt * 16 + lr];
#pragma unroll
        for (int r = 0; r < 4; ++r) {
          int jj = jt * 16 + lr;
          int sl = w * 16 + lh * 4 + r;
          *(unsigned short*)(sm + jj * 128 + ((sl * 2) ^ ((jj & 7) << 4))) =
              f2bf(acc[jt][r] + bb);
        }
      }
      __syncthreads();
#pragma unroll
      for (int g2 = 0; g2 < 4; ++g2) {
        int jj = w * 32 + g2 * 8 + (l >> 3);
        s16x8 row = *(const s16x8*)(sm + jj * 128 + (((l & 7) * 16) ^ ((jj & 7) << 4)));
        *(s16x8*)(Vt + jj * 8192 + s0 + (l & 7) * 8) = row;
      }
    }
  }
}

// ---------------- flash attention: 2 heads x 128 q-tiles of 64 ----------------
__global__ __launch_bounds__(256) void attn_kernel(
    const unsigned short* __restrict__ Qb, const unsigned short* __restrict__ Kb,
    const unsigned short* __restrict__ Vt, unsigned short* __restrict__ Ot) {
  __shared__ __align__(16) unsigned char sm[40960];  // K0,K1,V0,V1 (8KB each), P @32768
  const int tid = threadIdx.x;
  const int h = blockIdx.x & 1, q0 = (blockIdx.x >> 1) * 64;
  const int w = tid >> 6, l = tid & 63, lr = l & 15, lh = l >> 4;
  const int lswz = (lr & 7) << 4;

  bf16x8 qf[2];
#pragma unroll
  for (int ks = 0; ks < 2; ++ks)
    qf[ks] = __builtin_bit_cast(
        bf16x8, *(const s16x8*)(Qb + (q0 + w * 16 + lr) * 128 + h * 64 + ks * 32 + lh * 8));

  f32x4 acc[4];
  float m_[4], l_[4];
#pragma unroll
  for (int i = 0; i < 4; ++i) { acc[i] = (f32x4){0.f,0.f,0.f,0.f}; m_[i] = -1e30f; l_[i] = 0.f; }

  int srow[2], soff[2], sldsoff[2];
#pragma unroll
  for (int i = 0; i < 2; ++i) {
    int ch = tid + i * 256;
    srow[i] = ch >> 3;
    soff[i] = (ch & 7) * 8;  // ushort offset, 16B granule
    sldsoff[i] = srow[i] * 128 + ((soff[i] * 2) ^ ((srow[i] & 7) << 4));
  }

  {  // prologue: stage tile 0 into buffer 0
#pragma unroll
    for (int i = 0; i < 2; ++i) {
      i32x4 kv = *(const i32x4*)(Kb + srow[i] * 128 + h * 64 + soff[i]);
      i32x4 vv = *(const i32x4*)(Vt + (h * 64 + srow[i]) * 8192 + soff[i]);
      *(i32x4*)(sm + sldsoff[i]) = kv;
      *(i32x4*)(sm + 16384 + sldsoff[i]) = vv;
    }
  }
  __syncthreads();

  const float sc = 0.18033688011112042f;  // 1/sqrt(64) * log2(e)

  for (int t = 0; t < 128; ++t) {
    const int cur = t & 1;
    i32x4 nk[2], nv[2];
    if (t < 127) {
#pragma unroll
      for (int i = 0; i < 2; ++i) {
        nk[i] = *(const i32x4*)(Kb + ((t + 1) * 64 + srow[i]) * 128 + h * 64 + soff[i]);
        nv[i] = *(const i32x4*)(Vt + (h * 64 + srow[i]) * 8192 + (t + 1) * 64 + soff[i]);
      }
    }
    const unsigned char* kb = sm + cur * 8192;
    const unsigned char* vb = sm + 16384 + cur * 8192;
    unsigned char* pb = sm + 32768;

    // S = Q K^T for 64 keys
    f32x4 s4[4];
#pragma unroll
    for (int nt = 0; nt < 4; ++nt) s4[nt] = (f32x4){0.f,0.f,0.f,0.f};
#pragma unroll
    for (int ks = 0; ks < 2; ++ks) {
#pragma unroll
      for (int nt = 0; nt < 4; ++nt) {
        bf16x8 kf = lds_frag(kb + (nt * 16 + lr) * 128 + ((ks * 64 + lh * 16) ^ lswz));
        s4[nt] = mfma16(qf[ks], kf, s4[nt]);
      }
    }

    // online softmax (row q = w*16 + lh*4 + r; reduce over the 16 key-lanes)
    float p[4][4];
#pragma unroll
    for (int r = 0; r < 4; ++r) {
      float mx = fmaxf(fmaxf(s4[0][r], s4[1][r]), fmaxf(s4[2][r], s4[3][r]));
      mx = redmax16(mx) * sc;
      float mn = fmaxf(m_[r], mx);
      float al = __builtin_amdgcn_exp2f(m_[r] - mn);
      m_[r] = mn;
      float rs = 0.f;
#pragma unroll
      for (int nt = 0; nt < 4; ++nt) {
        p[nt][r] = __builtin_amdgcn_exp2f(fmaf(s4[nt][r], sc, -mn));
        rs += p[nt][r];
      }
      rs = redsum16(rs);
      l_[r] = l_[r] * al + rs;
#pragma unroll
      for (int ct = 0; ct < 4; ++ct) acc[ct][r] *= al;
    }

    // P round-trip through swizzled LDS
    const int qrow = w * 16 + lh * 4;
#pragma unroll
    for (int r = 0; r < 4; ++r) {
      int q = qrow + r;
      unsigned char* prow = pb + q * 128;
      int qswz = (q & 7) << 4;
#pragma unroll
      for (int nt = 0; nt < 4; ++nt)
        *(unsigned short*)(prow + (((nt * 16 + lr) * 2) ^ qswz)) = f2bf(p[nt][r]);
    }
    asm volatile("s_waitcnt lgkmcnt(0)" ::: "memory");
    __builtin_amdgcn_sched_barrier(0);

    bf16x8 pa[2];
#pragma unroll
    for (int ks = 0; ks < 2; ++ks)
      pa[ks] = lds_frag(pb + (w * 16 + lr) * 128 + ((ks * 64 + lh * 16) ^ lswz));
#pragma unroll
    for (int ks = 0; ks < 2; ++ks) {
#pragma unroll
      for (int ct = 0; ct < 4; ++ct) {
        bf16x8 vf = lds_frag(vb + (ct * 16 + lr) * 128 + ((ks * 64 + lh * 16) ^ lswz));
        acc[ct] = mfma16(pa[ks], vf, acc[ct]);
      }
    }

    __syncthreads();
    if (t < 127) {
#pragma unroll
      for (int i = 0; i < 2; ++i) {
        *(i32x4*)(sm + (cur ^ 1) * 8192 + sldsoff[i]) = nk[i];
        *(i32x4*)(sm + 16384 + (cur ^ 1) * 8192 + sldsoff[i]) = nv[i];
      }
    }
    __syncthreads();
  }

  // epilogue: O/l, transpose through LDS, store Ot[j][s]
  float inv[4];
#pragma unroll
  for (int r = 0; r < 4; ++r) inv[r] = 1.0f / l_[r];
  __syncthreads();
  unsigned char* ob = sm + 32768;
#pragma unroll
  for (int ct = 0; ct < 4; ++ct) {
    int d = ct * 16 + lr;
#pragma unroll
    for (int r = 0; r < 4; ++r) {
      int q = w * 16 + lh * 4 + r;
      *(unsigned short*)(ob + d * 128 + ((q * 2) ^ ((d & 7) << 4))) = f2bf(acc[ct][r] * inv[r]);
    }
  }
  __syncthreads();
#pragma unroll
  for (int p2 = 0; p2 < 2; ++p2) {
    int d = w * 16 + p2 * 8 + (l >> 3);
    s16x8 row = *(const s16x8*)(ob + d * 128 + (((l & 7) * 16) ^ ((d & 7) << 4)));
    *(s16x8*)(Ot + (h * 64 + d) * 8192 + q0 + (l & 7) * 8) = row;
  }
}

// ---------------- proj: out[(c,hp)][wq] = Ot[(c,hp)][wp] Wp^T + bp (f32 out) ---
__global__ __launch_bounds__(256) void proj_kernel(
    const unsigned short* __restrict__ Ot, const unsigned short* __restrict__ wbf,
    const float* __restrict__ bp, float* __restrict__ out) {
  __shared__ __align__(16) unsigned char sm[16384];
  const int tid = threadIdx.x;
  const int r0 = blockIdx.x * 64;
#pragma unroll
  for (int i = 0; i < 4; ++i) {
    int chk = tid + 256 * i;
    i32x4 v = *(const i32x4*)(Ot + r0 * 128 + chk * 8);
    int row = chk >> 4, off = (chk & 15) * 16;
    *(i32x4*)(sm + row * 256 + (off ^ ((row & 7) << 4))) = v;
  }
  __syncthreads();
  const int w = tid >> 6, l = tid & 63, lr = l & 15, lh = l >> 4;
  f32x4 acc[8];
#pragma unroll
  for (int jt = 0; jt < 8; ++jt) acc[jt] = (f32x4){0.f, 0.f, 0.f, 0.f};
  const unsigned char* wsrc = (const unsigned char*)wbf + 3 * 32768;
#pragma unroll
  for (int ks = 0; ks < 4; ++ks) {
    bf16x8 a = lds_frag(sm + (w * 16 + lr) * 256 + ((ks * 64 + lh * 16) ^ ((lr & 7) << 4)));
#pragma unroll
    for (int jt = 0; jt < 8; ++jt) {
      bf16x8 bb = __builtin_bit_cast(
          bf16x8, *(const s16x8*)(wsrc + (jt * 16 + lr) * 256 + ks * 64 + lh * 16));
      acc[jt] = mfma16(a, bb, acc[jt]);
    }
  }
#pragma unroll
  for (int jt = 0; jt < 8; ++jt) {
    float bb = bp[jt * 16 + lr];
#pragma unroll
    for (int r = 0; r < 4; ++r)
      out[(r0 + w * 16 + lh * 4 + r) * 128 + jt * 16 + lr] = acc[jt][r] + bb;
  }
}

extern "C" void kernel_launch(void* const* d_in, const int* in_sizes, int n_in,
                              void* d_out, int out_size, void* d_ws, size_t ws_size,
                              hipStream_t stream) {
  const float* x   = (const float*)d_in[0];
  const float* wav = (const float*)d_in[1];
  const float* Wq  = (const float*)d_in[2];
  const float* bq  = (const float*)d_in[3];
  const float* Wk  = (const float*)d_in[4];
  const float* bk  = (const float*)d_in[5];
  const float* Wv  = (const float*)d_in[6];
  const float* bv  = (const float*)d_in[7];
  const float* Wp  = (const float*)d_in[8];
  const float* bp  = (const float*)d_in[9];
  (void)in_sizes; (void)n_in; (void)out_size; (void)ws_size;

  unsigned char* ws = (unsigned char*)d_ws;
  unsigned short* Qb  = (unsigned short*)(ws);                 // [8192][128] bf16, 2MB
  unsigned short* Kb  = (unsigned short*)(ws + 2097152);       // [8192][128]
  unsigned short* Vt  = (unsigned short*)(ws + 4194304);       // [128][8192]
  unsigned short* Ot  = (unsigned short*)(ws + 6291456);       // [128][8192]
  unsigned short* Wbf = (unsigned short*)(ws + 8388608);       // 4x[128][128] bf16

  prep_w_kernel<<<64, 256, 0, stream>>>(Wq, Wk, Wv, Wp, Wbf);
  qkv_kernel<<<128, 256, 0, stream>>>(x, wav, Wbf, bq, bk, bv, Qb, Kb, Vt);
  attn_kernel<<<256, 256, 0, stream>>>(Qb, Kb, Vt, Ot);
  proj_kernel<<<128, 256, 0, stream>>>(Ot, Wbf, bp, (float*)d_out);
}